// Round 11
// baseline (259.791 us; speedup 1.0000x reference)
//
#include <hip/hip_runtime.h>
#include <stdint.h>

// Problem constants (MultiHeadAttention: B=4,T=2048,C=1024,H=16,Dh=64)
#define EMB   1024
#define NH    16
#define DH    64
#define NB    4
#define NT    2048
#define BT    (NB*NT)       // 8192 rows
#define NQKV  (3*EMB)       // 3072
// SCALE * log2(e) = 0.125 * 1.4426950408889634  (folded into Q at QKV epilogue)
#define CL2E  0.1803368801111204f

typedef short v4s __attribute__((ext_vector_type(4)));
typedef short v8s __attribute__((ext_vector_type(8)));
typedef float v4f __attribute__((ext_vector_type(4)));

__device__ __forceinline__ unsigned short f2bf(float f) {
  unsigned int u = __builtin_bit_cast(unsigned int, f);
  u += 0x7fffu + ((u >> 16) & 1u);
  return (unsigned short)(u >> 16);
}

// async global->LDS, 16B per lane (dest = wave-uniform base + lane*16).
__device__ __forceinline__ void gld16(const unsigned short* g, unsigned short* l) {
  __builtin_amdgcn_global_load_lds(
      (const __attribute__((address_space(1))) unsigned int*)g,
      (__attribute__((address_space(3))) unsigned int*)l, 16, 0, 0);
}

// pack 2 f32 -> 2 bf16 (RTNE) in one VALU op (no builtin on gfx950; guide T12)
__device__ __forceinline__ unsigned int cvtpk_bf16(float lo, float hi) {
  unsigned int r;
  asm("v_cvt_pk_bf16_f32 %0, %1, %2" : "=v"(r) : "v"(lo), "v"(hi));
  return r;
}

// exp2 the 8 accumulator values of an St tile-pair and pack to a v8s
// B-operand fragment for mfma_f32_16x16x32_bf16 (elements j=0..7 = k=quad*8+j).
__device__ __forceinline__ v8s exppack8(v4f a, v4f b) {
  uint4 d;
  d.x = cvtpk_bf16(__builtin_amdgcn_exp2f(a[0]), __builtin_amdgcn_exp2f(a[1]));
  d.y = cvtpk_bf16(__builtin_amdgcn_exp2f(a[2]), __builtin_amdgcn_exp2f(a[3]));
  d.z = cvtpk_bf16(__builtin_amdgcn_exp2f(b[0]), __builtin_amdgcn_exp2f(b[1]));
  d.w = cvtpk_bf16(__builtin_amdgcn_exp2f(b[2]), __builtin_amdgcn_exp2f(b[3]));
  return __builtin_bit_cast(v8s, d);
}

// ---------------------------------------------------------------- cast x->bf16
__global__ __launch_bounds__(256) void cast_bf16_k(
    const float* __restrict__ in, unsigned short* __restrict__ out, int n8) {
  int i = blockIdx.x * 256 + threadIdx.x;
  if (i >= n8) return;
  const float4* p = (const float4*)in + (size_t)i * 2;
  float4 a = p[0], b = p[1];
  union { unsigned short s[8]; uint4 u; } o;
  o.s[0] = f2bf(a.x); o.s[1] = f2bf(a.y); o.s[2] = f2bf(a.z); o.s[3] = f2bf(a.w);
  o.s[4] = f2bf(b.x); o.s[5] = f2bf(b.y); o.s[6] = f2bf(b.z); o.s[7] = f2bf(b.w);
  ((uint4*)out)[i] = o.u;
}

// ------------------------------------------- transpose+cast W(R,C)->Wt(C,R) bf16
__global__ __launch_bounds__(256) void transpose_cast_k(
    const float* __restrict__ in, unsigned short* __restrict__ out, int R, int C) {
  __shared__ float tile[32][33];
  int t = threadIdx.x, lr = t >> 5, lc = t & 31;
  int r0 = blockIdx.y * 32, c0 = blockIdx.x * 32;
#pragma unroll
  for (int i = 0; i < 32; i += 8)
    tile[lr + i][lc] = in[(size_t)(r0 + lr + i) * C + c0 + lc];
  __syncthreads();
#pragma unroll
  for (int i = 0; i < 32; i += 8)
    out[(size_t)(c0 + lr + i) * R + r0 + lc] = f2bf(tile[lc][lr + i]);
}

// ---------------------------------------------------------------- GEMM A * B^T
// (unchanged from R7 — verified.) BK=64, 2-barrier-per-iter skeleton, 32KB LDS.
// stage: call i covers rows i*32+(t>>3); slot t&7; global chunk
//        jS=(t&7)^s(row), s(r)=((r&3)<<1)|((r>>3)&1); LDS dest linear.
// read:  chunk (kk*4+quad)^s(m16) of row (w*64+mi*16+m16).
// MODE 0 only now: scatters Q (pre-scaled by CL2E), K (b,h,t,d), V (b,h,d,t).
template <int MODE>
__global__ __launch_bounds__(256, 2) void gemm_bt(
    const unsigned short* __restrict__ A, const unsigned short* __restrict__ Bt,
    const float* __restrict__ bias, float* __restrict__ Co,
    unsigned short* __restrict__ q_out, unsigned short* __restrict__ k_out,
    unsigned short* __restrict__ v_out, int M, int N, int K) {
  const int t = threadIdx.x;
  const int wave = t >> 6, lane = t & 63;
  const int m16 = lane & 15, quad = lane >> 4;
  const int wr = wave >> 1, wc = wave & 1;
  const int bm = blockIdx.y * 128, bn = blockIdx.x * 128;

  __shared__ unsigned short As[128 * 64];   // 16 KB
  __shared__ unsigned short Bs[128 * 64];   // 16 KB

  v4f acc[4][4];
#pragma unroll
  for (int mi = 0; mi < 4; mi++)
#pragma unroll
    for (int ni = 0; ni < 4; ni++) acc[mi][ni] = (v4f){0.f, 0.f, 0.f, 0.f};

  // staging addresses (see header comment)
  const int rS = t >> 3;
  const int jS = (t & 7) ^ (((rS & 3) << 1) | ((rS >> 3) & 1));
  const unsigned short* gA = A + (size_t)(bm + rS) * K + jS * 8;
  const unsigned short* gB = Bt + (size_t)(bn + rS) * K + jS * 8;

  // fragment-read bases
  const int sA = ((m16 & 3) << 1) | ((m16 >> 3) & 1);
  const int c0 = quad ^ sA;                       // chunk slot for kk=0
  const unsigned short* aBase = &As[(wr * 64 + m16) * 64];
  const unsigned short* bBase = &Bs[(wc * 64 + m16) * 64];

  const int nkt = K >> 6;
  for (int kt = 0; kt < nkt; ++kt) {
#pragma unroll
    for (int i = 0; i < 4; ++i) {
      gld16(gA + (size_t)(i * 32) * K, &As[(i * 256 + t) * 8]);
      gld16(gB + (size_t)(i * 32) * K, &Bs[(i * 256 + t) * 8]);
    }
    gA += 64; gB += 64;
    __syncthreads();

#pragma unroll
    for (int kk = 0; kk < 2; ++kk) {
      const int co = (c0 ^ (kk * 4)) * 8;
      v8s a[4], b[4];
#pragma unroll
      for (int mi = 0; mi < 4; mi++)
        a[mi] = *(const v8s*)(aBase + mi * 16 * 64 + co);
#pragma unroll
      for (int ni = 0; ni < 4; ni++)
        b[ni] = *(const v8s*)(bBase + ni * 16 * 64 + co);
#pragma unroll
      for (int mi = 0; mi < 4; mi++)
#pragma unroll
        for (int ni = 0; ni < 4; ni++)
          acc[mi][ni] = __builtin_amdgcn_mfma_f32_16x16x32_bf16(a[mi], b[ni], acc[mi][ni], 0, 0, 0);
    }
    __syncthreads();
  }

  if (MODE == 0) {
#pragma unroll
    for (int mi = 0; mi < 4; mi++) {
#pragma unroll
      for (int ni = 0; ni < 4; ni++) {
        int col = bn + wc * 64 + ni * 16 + m16;
        int which = col >> 10;
        int h = (col >> 6) & 15, d = col & 63;
        float bv = bias[col];
        float sc = (which == 0) ? CL2E : 1.f;
        int row0 = bm + wr * 64 + mi * 16 + quad * 4;
        int bb = row0 >> 11, tt0 = row0 & 2047;
        float v0 = (acc[mi][ni][0] + bv) * sc, v1 = (acc[mi][ni][1] + bv) * sc;
        float v2 = (acc[mi][ni][2] + bv) * sc, v3 = (acc[mi][ni][3] + bv) * sc;
        if (which == 2) {
          ushort4 pk; pk.x = f2bf(v0); pk.y = f2bf(v1); pk.z = f2bf(v2); pk.w = f2bf(v3);
          *(ushort4*)&v_out[(((size_t)(bb * NH + h)) * DH + d) * NT + tt0] = pk;
        } else {
          unsigned short* dst = (which == 0) ? q_out : k_out;
          size_t idx = (((size_t)(bb * NH + h)) * NT + tt0) * DH + d;
          dst[idx] = f2bf(v0); dst[idx + DH] = f2bf(v1);
          dst[idx + 2 * DH] = f2bf(v2); dst[idx + 3 * DH] = f2bf(v3);
        }
      }
    }
  } else {
#pragma unroll
    for (int mi = 0; mi < 4; mi++) {
#pragma unroll
      for (int ni = 0; ni < 4; ni++) {
        int col = bn + wc * 64 + ni * 16 + m16;
        float bv = bias[col];
#pragma unroll
        for (int r = 0; r < 4; r++) {
          int row = bm + wr * 64 + mi * 16 + quad * 4 + r;
          Co[(size_t)row * N + col] = acc[mi][ni][r] + bv;
        }
      }
    }
  }
}

// ------------------------------------------- GEMM MODE-1 (128x64 tile, BK=64)
// R11: dedicated out-projection kernel. Old MODE-1 grid was (8,64)=512 blocks
// = 2 blocks/CU — starved TLP (same serialized-loop regime R5's flash showed).
// BN=64 doubles the grid: (16,64)=1024 blocks = 4 blocks/CU, LDS 24KB.
// Same verified skeleton: stage (4+2 gld16, linear dest, pre-swizzled src) ->
// barrier -> 2xK=32 compute -> barrier. Same s(r)=((r&3)<<1)|((r>>3)&1):
// A-read row = w*32+mi*16+m16, B-read row = ni*16+m16 — row bits {0,1,3}
// equal m16 bits in both, so read swizzle sA is unchanged (verified algebra).
// Wave w owns rows w*32..w*32+31 (acc[2][4]); per iter 6 ds_read + 16 MFMA.
__global__ __launch_bounds__(256, 4) void gemm_bt_m1(
    const unsigned short* __restrict__ A, const unsigned short* __restrict__ Bt,
    const float* __restrict__ bias, float* __restrict__ Co, int M, int N, int K) {
  const int t = threadIdx.x;
  const int w = t >> 6, lane = t & 63;
  const int m16 = lane & 15, quad = lane >> 4;
  const int bm = blockIdx.y * 128, bn = blockIdx.x * 64;

  __shared__ unsigned short As[128 * 64];   // 16 KB
  __shared__ unsigned short Bs[64 * 64];    //  8 KB

  v4f acc[2][4];
#pragma unroll
  for (int mi = 0; mi < 2; mi++)
#pragma unroll
    for (int ni = 0; ni < 4; ni++) acc[mi][ni] = (v4f){0.f, 0.f, 0.f, 0.f};

  // staging: rS = t>>3 covers 32 rows/call; A 4 calls, B 2 calls.
  const int rS = t >> 3;
  const int jS = (t & 7) ^ (((rS & 3) << 1) | ((rS >> 3) & 1));
  const unsigned short* gA = A + (size_t)(bm + rS) * K + jS * 8;
  const unsigned short* gB = Bt + (size_t)(bn + rS) * K + jS * 8;

  // fragment-read bases
  const int sA = ((m16 & 3) << 1) | ((m16 >> 3) & 1);
  const int c0 = quad ^ sA;
  const unsigned short* aBase = &As[(w * 32 + m16) * 64];
  const unsigned short* bBase = &Bs[m16 * 64];

  const int nkt = K >> 6;
  for (int kt = 0; kt < nkt; ++kt) {
#pragma unroll
    for (int i = 0; i < 4; ++i)
      gld16(gA + (size_t)(i * 32) * K, &As[(i * 256 + t) * 8]);
#pragma unroll
    for (int i = 0; i < 2; ++i)
      gld16(gB + (size_t)(i * 32) * K, &Bs[(i * 256 + t) * 8]);
    gA += 64; gB += 64;
    __syncthreads();

#pragma unroll
    for (int kk = 0; kk < 2; ++kk) {
      const int co = (c0 ^ (kk * 4)) * 8;
      v8s a[2], b[4];
#pragma unroll
      for (int mi = 0; mi < 2; mi++)
        a[mi] = *(const v8s*)(aBase + mi * 16 * 64 + co);
#pragma unroll
      for (int ni = 0; ni < 4; ni++)
        b[ni] = *(const v8s*)(bBase + ni * 16 * 64 + co);
#pragma unroll
      for (int mi = 0; mi < 2; mi++)
#pragma unroll
        for (int ni = 0; ni < 4; ni++)
          acc[mi][ni] = __builtin_amdgcn_mfma_f32_16x16x32_bf16(a[mi], b[ni], acc[mi][ni], 0, 0, 0);
    }
    __syncthreads();
  }

#pragma unroll
  for (int mi = 0; mi < 2; mi++) {
#pragma unroll
    for (int ni = 0; ni < 4; ni++) {
      int col = bn + ni * 16 + m16;
      float bv = bias[col];
#pragma unroll
      for (int r = 0; r < 4; r++) {
        int row = bm + w * 32 + mi * 16 + quad * 4 + r;
        Co[(size_t)row * N + col] = acc[mi][ni][r] + bv;
      }
    }
  }
}

// ---------------------------------------------------------------- flash attention
// (unchanged from R7 — verified: QBLK=128, KVBLK=64, 16KB LDS, 4 blocks/CU.
//  R9's setprio was slightly negative and is not included. Flash config FROZEN:
//  R2/R3 dbuf, R4 grid-remap, R10 QBLK=64 all failed refcheck — family limits.)
// Q (pre-scaled by CL2E),K: (B*H, T, Dh) bf16. Vt: (B*H, Dh, T) bf16.
// Out: (B*T, EMB) bf16.  Block = 4 waves, 128 Q rows (32/wave).
__global__ __launch_bounds__(256, 4) void flash_attn(
    const unsigned short* __restrict__ Qg, const unsigned short* __restrict__ Kg,
    const unsigned short* __restrict__ Vtg, unsigned short* __restrict__ Og) {
  const int t = threadIdx.x;
  const int w = t >> 6, lane = t & 63;
  const int m16 = lane & 15, quad = lane >> 4;
  const int qt = blockIdx.x, bh = blockIdx.y;
  const int b = bh >> 4, h = bh & 15;

  __shared__ unsigned short Ks[64 * 64];      // swizzled [key][d]   (8 KB)
  __shared__ unsigned short Vt[64 * 64];      // swizzled [d][key]   (8 KB)

  const size_t baseq = (size_t)bh * NT * DH;  // Q,K: (t,d)
  const size_t basev = (size_t)bh * DH * NT;  // Vt:  (d,t)

  // Q fragments: two 16-row tiles (B-operand layout == A layout for this shape)
  v8s qf[2][2];
#pragma unroll
  for (int tq = 0; tq < 2; tq++) {
    int qrow = qt * 128 + w * 32 + tq * 16 + m16;
#pragma unroll
    for (int kk = 0; kk < 2; kk++)
      qf[tq][kk] = *(const v8s*)&Qg[baseq + (size_t)qrow * DH + kk * 32 + quad * 8];
  }

  v4f accO[2][4], accL[2];
#pragma unroll
  for (int tq = 0; tq < 2; tq++) {
#pragma unroll
    for (int i = 0; i < 4; i++) accO[tq][i] = (v4f){0.f, 0.f, 0.f, 0.f};
    accL[tq] = (v4f){0.f, 0.f, 0.f, 0.f};
  }
  const v4f zero4 = (v4f){0.f, 0.f, 0.f, 0.f};
  const v8s ones8 = (v8s){(short)0x3F80, (short)0x3F80, (short)0x3F80, (short)0x3F80,
                          (short)0x3F80, (short)0x3F80, (short)0x3F80, (short)0x3F80};

  // ---- loop-invariant addresses
  const int rK = t >> 3, jK = (t & 7) ^ (((rK & 3) << 1) | ((rK >> 3) & 1));
  const int dV = t >> 3, jV = (t & 7) ^ (dV & 7);
  const unsigned short* gK = &Kg[baseq + (size_t)rK * DH + jK * 8];
  const unsigned short* gV = &Vtg[basev + (size_t)dV * NT + jV * 8];
  // K-frag bases (A-operand of St): permuted rows, chunks kk*4+quad, swizzle sP.
  const int keyA = ((m16 >> 2) << 3) | (m16 & 3);                 // tile a row->key
  const int sP = ((m16 & 3) << 1) | ((m16 >> 2) & 1);             // == s(keyA) == s(keyA+4)
  const unsigned short* ka0 = &Ks[ keyA      * 64 + ((0 + quad) ^ sP) * 8];  // kk=0
  const unsigned short* ka1 = &Ks[ keyA      * 64 + ((4 + quad) ^ sP) * 8];  // kk=1
  const unsigned short* kb0 = &Ks[(keyA + 4) * 64 + ((0 + quad) ^ sP) * 8];
  const unsigned short* kb1 = &Ks[(keyA + 4) * 64 + ((4 + quad) ^ sP) * 8];
  // V-frag base (A-operand of PV, 16x16x32): row d = ni2*16+m16,
  // keys nj*32 + quad*8..+7 = chunk c = nj*4+quad at slot c ^ (m16&7).
  const unsigned short* vBase = &Vt[m16 * 64];

  for (int kt = 0; kt < NT / 64; ++kt) {
    __syncthreads();  // all waves done reading previous Ks/Vt
#pragma unroll
    for (int i = 0; i < 2; ++i)
      gld16(gK + (size_t)(i * 32) * DH, &Ks[(i * 256 + t) * 8]);
#pragma unroll
    for (int i = 0; i < 2; ++i)
      gld16(gV + (size_t)(i * 32) * NT, &Vt[(i * 256 + t) * 8]);
    gK += 64 * DH;
    gV += 64;
    __syncthreads();

    // St tile-pairs -> exp2 -> packed v8s P fragments (in-register, no LDS)
    v8s pp[2][2];
#pragma unroll
    for (int nj = 0; nj < 2; nj++) {
      const int o = nj * 2048;                 // 32 keys * 64 shorts
      v8s kA0 = *(const v8s*)(ka0 + o);
      v8s kA1 = *(const v8s*)(ka1 + o);
      v8s kB0 = *(const v8s*)(kb0 + o);
      v8s kB1 = *(const v8s*)(kb1 + o);
      v4f s0a = __builtin_amdgcn_mfma_f32_16x16x32_bf16(kA0, qf[0][0], zero4, 0, 0, 0);
      s0a = __builtin_amdgcn_mfma_f32_16x16x32_bf16(kA1, qf[0][1], s0a, 0, 0, 0);
      v4f s1a = __builtin_amdgcn_mfma_f32_16x16x32_bf16(kA0, qf[1][0], zero4, 0, 0, 0);
      s1a = __builtin_amdgcn_mfma_f32_16x16x32_bf16(kA1, qf[1][1], s1a, 0, 0, 0);
      v4f s0b = __builtin_amdgcn_mfma_f32_16x16x32_bf16(kB0, qf[0][0], zero4, 0, 0, 0);
      s0b = __builtin_amdgcn_mfma_f32_16x16x32_bf16(kB1, qf[0][1], s0b, 0, 0, 0);
      v4f s1b = __builtin_amdgcn_mfma_f32_16x16x32_bf16(kB0, qf[1][0], zero4, 0, 0, 0);
      s1b = __builtin_amdgcn_mfma_f32_16x16x32_bf16(kB1, qf[1][1], s1b, 0, 0, 0);
      pp[0][nj] = exppack8(s0a, s0b);
      pp[1][nj] = exppack8(s1a, s1b);
    }

    // O^T += V^T * P  (16x16x32, P straight from registers); L += 1 * P
#pragma unroll
    for (int nj = 0; nj < 2; nj++) {
      accL[0] = __builtin_amdgcn_mfma_f32_16x16x32_bf16(ones8, pp[0][nj], accL[0], 0, 0, 0);
      accL[1] = __builtin_amdgcn_mfma_f32_16x16x32_bf16(ones8, pp[1][nj], accL[1], 0, 0, 0);
      const int slot = ((nj * 4 + quad) ^ (m16 & 7)) * 8;
#pragma unroll
      for (int ni2 = 0; ni2 < 4; ni2++) {
        v8s vf = *(const v8s*)(vBase + ni2 * 16 * 64 + slot);
        accO[0][ni2] = __builtin_amdgcn_mfma_f32_16x16x32_bf16(vf, pp[0][nj], accO[0][ni2], 0, 0, 0);
        accO[1][ni2] = __builtin_amdgcn_mfma_f32_16x16x32_bf16(vf, pp[1][nj], accO[1][ni2], 0, 0, 0);
      }
    }
  }

  // epilogue: O^T tiles: lane (col=qrow=m16, quad) holds d = ni2*16+quad*4+r.
  // accL: all r-copies equal L[qrow=m16]. 4 consecutive d -> one 8B store.
#pragma unroll
  for (int tq = 0; tq < 2; tq++) {
    float inv = 1.f / accL[tq][0];
    int trow = qt * 128 + w * 32 + tq * 16 + m16;
    size_t ob = ((size_t)b * NT + trow) * EMB + h * DH;
#pragma unroll
    for (int ni2 = 0; ni2 < 4; ni2++) {
      float v0 = accO[tq][ni2][0] * inv, v1 = accO[tq][ni2][1] * inv;
      float v2 = accO[tq][ni2][2] * inv, v3 = accO[tq][ni2][3] * inv;
      uint2 d;
      d.x = (unsigned int)f2bf(v0) | ((unsigned int)f2bf(v1) << 16);
      d.y = (unsigned int)f2bf(v2) | ((unsigned int)f2bf(v3) << 16);
      *(uint2*)&Og[ob + ni2 * 16 + quad * 4] = d;
    }
  }
}

// ---------------------------------------------------------------- launch
extern "C" void kernel_launch(void* const* d_in, const int* in_sizes, int n_in,
                              void* d_out, int out_size, void* d_ws, size_t ws_size,
                              hipStream_t stream) {
  const float* x     = (const float*)d_in[0];
  const float* w_qkv = (const float*)d_in[1];
  const float* b_qkv = (const float*)d_in[2];
  const float* w_out = (const float*)d_in[3];
  const float* b_out = (const float*)d_in[4];
  float* out = (float*)d_out;

  unsigned short* xb    = (unsigned short*)d_ws;            // 8192*1024
  unsigned short* wqkvT = xb    + (size_t)BT * EMB;         // 3072*1024
  unsigned short* woutT = wqkvT + (size_t)NQKV * EMB;       // 1024*1024
  unsigned short* qb    = woutT + (size_t)EMB * EMB;        // (b,h,t,d), pre-scaled
  unsigned short* kb    = qb    + (size_t)NB * NH * NT * DH; // (b,h,t,d)
  unsigned short* vb    = kb    + (size_t)NB * NH * NT * DH; // (b,h,d,t) transposed!
  unsigned short* ao    = vb    + (size_t)NB * NH * NT * DH; // 8192*1024

  cast_bf16_k<<<(BT * EMB / 8 + 255) / 256, 256, 0, stream>>>(x, xb, BT * EMB / 8);
  transpose_cast_k<<<dim3(NQKV / 32, EMB / 32), 256, 0, stream>>>(w_qkv, wqkvT, EMB, NQKV);
  transpose_cast_k<<<dim3(EMB / 32, EMB / 32), 256, 0, stream>>>(w_out, woutT, EMB, EMB);

  gemm_bt<0><<<dim3(NQKV / 128, BT / 128), 256, 0, stream>>>(
      xb, wqkvT, b_qkv, nullptr, qb, kb, vb, BT, NQKV, EMB);

  flash_attn<<<dim3(NT / 128, NB * NH), 256, 0, stream>>>(qb, kb, vb, ao);

  gemm_bt_m1<<<dim3(EMB / 64, BT / 128), 256, 0, stream>>>(
      ao, woutT, b_out, out, BT, EMB, EMB);
}

// Round 12
// 248.708 us; speedup vs baseline: 1.0446x; 1.0446x over previous
//
#include <hip/hip_runtime.h>
#include <stdint.h>

// Problem constants (MultiHeadAttention: B=4,T=2048,C=1024,H=16,Dh=64)
#define EMB   1024
#define NH    16
#define DH    64
#define NB    4
#define NT    2048
#define BT    (NB*NT)       // 8192 rows
#define NQKV  (3*EMB)       // 3072
// SCALE * log2(e) = 0.125 * 1.4426950408889634  (folded into Q at QKV epilogue)
#define CL2E  0.1803368801111204f

typedef short v4s __attribute__((ext_vector_type(4)));
typedef short v8s __attribute__((ext_vector_type(8)));
typedef float v4f __attribute__((ext_vector_type(4)));

__device__ __forceinline__ unsigned short f2bf(float f) {
  unsigned int u = __builtin_bit_cast(unsigned int, f);
  u += 0x7fffu + ((u >> 16) & 1u);
  return (unsigned short)(u >> 16);
}

// async global->LDS, 16B per lane (dest = wave-uniform base + lane*16).
__device__ __forceinline__ void gld16(const unsigned short* g, unsigned short* l) {
  __builtin_amdgcn_global_load_lds(
      (const __attribute__((address_space(1))) unsigned int*)g,
      (__attribute__((address_space(3))) unsigned int*)l, 16, 0, 0);
}

// pack 2 f32 -> 2 bf16 (RTNE) in one VALU op (no builtin on gfx950; guide T12)
__device__ __forceinline__ unsigned int cvtpk_bf16(float lo, float hi) {
  unsigned int r;
  asm("v_cvt_pk_bf16_f32 %0, %1, %2" : "=v"(r) : "v"(lo), "v"(hi));
  return r;
}

// exp2 the 8 accumulator values of an St tile-pair and pack to a v8s
// B-operand fragment for mfma_f32_16x16x32_bf16 (elements j=0..7 = k=quad*8+j).
__device__ __forceinline__ v8s exppack8(v4f a, v4f b) {
  uint4 d;
  d.x = cvtpk_bf16(__builtin_amdgcn_exp2f(a[0]), __builtin_amdgcn_exp2f(a[1]));
  d.y = cvtpk_bf16(__builtin_amdgcn_exp2f(a[2]), __builtin_amdgcn_exp2f(a[3]));
  d.z = cvtpk_bf16(__builtin_amdgcn_exp2f(b[0]), __builtin_amdgcn_exp2f(b[1]));
  d.w = cvtpk_bf16(__builtin_amdgcn_exp2f(b[2]), __builtin_amdgcn_exp2f(b[3]));
  return __builtin_bit_cast(v8s, d);
}

// ----------------------------------------- fused preprocessing (R12)
// One dispatch replaces {cast x->bf16, transpose w_qkv, transpose w_out}.
// Blocks 0..4095: cast (identical body to the old cast_bf16_k).
// Blocks 4096..7167: transpose w_qkv (R=EMB rows, C=NQKV cols, 96x32 tiles).
// Blocks 7168..8191: transpose w_out (R=C=EMB, 32x32 tiles).
// Branching is block-uniform; transpose branch's __syncthreads is uniform.
__global__ __launch_bounds__(256) void prep_k(
    const float* __restrict__ x, unsigned short* __restrict__ xb,
    const float* __restrict__ w_qkv, unsigned short* __restrict__ wqkvT,
    const float* __restrict__ w_out, unsigned short* __restrict__ woutT) {
  const int bid = blockIdx.x;
  const int t = threadIdx.x;
  if (bid < 4096) {
    // cast: n8 = BT*EMB/8 = 1048576 = 4096*256 exactly
    int i = bid * 256 + t;
    const float4* p = (const float4*)x + (size_t)i * 2;
    float4 a = p[0], b = p[1];
    union { unsigned short s[8]; uint4 u; } o;
    o.s[0] = f2bf(a.x); o.s[1] = f2bf(a.y); o.s[2] = f2bf(a.z); o.s[3] = f2bf(a.w);
    o.s[4] = f2bf(b.x); o.s[5] = f2bf(b.y); o.s[6] = f2bf(b.z); o.s[7] = f2bf(b.w);
    ((uint4*)xb)[i] = o.u;
  } else {
    const float* in; unsigned short* out; int R, C, bx, by;
    if (bid < 4096 + 3072) {
      int b2 = bid - 4096; in = w_qkv; out = wqkvT; R = EMB; C = NQKV;
      bx = b2 % 96; by = b2 / 96;
    } else {
      int b3 = bid - 7168; in = w_out; out = woutT; R = EMB; C = EMB;
      bx = b3 & 31; by = b3 >> 5;
    }
    __shared__ float tile[32][33];
    int lr = t >> 5, lc = t & 31;
    int r0 = by * 32, c0 = bx * 32;
#pragma unroll
    for (int i = 0; i < 32; i += 8)
      tile[lr + i][lc] = in[(size_t)(r0 + lr + i) * C + c0 + lc];
    __syncthreads();
#pragma unroll
    for (int i = 0; i < 32; i += 8)
      out[(size_t)(c0 + lr + i) * R + r0 + lc] = f2bf(tile[lc][lr + i]);
  }
}

// ---------------------------------------------------------------- GEMM A * B^T
// (unchanged from R7 — verified.) BK=64, 2-barrier-per-iter skeleton, 32KB LDS.
// stage: call i covers rows i*32+(t>>3); slot t&7; global chunk
//        jS=(t&7)^s(row), s(r)=((r&3)<<1)|((r>>3)&1); LDS dest linear.
// read:  chunk (kk*4+quad)^s(m16) of row (w*64+mi*16+m16).
// MODE 0: scatters Q (pre-scaled by CL2E), K (b,h,t,d), V transposed (b,h,d,t).
// MODE 1: writes f32 C (M,N) + bias.  (R11's BN=64 m1 variant regressed -8us:
// halved per-block arithmetic intensity doubled A-stage traffic — reverted.)
template <int MODE>
__global__ __launch_bounds__(256, 2) void gemm_bt(
    const unsigned short* __restrict__ A, const unsigned short* __restrict__ Bt,
    const float* __restrict__ bias, float* __restrict__ Co,
    unsigned short* __restrict__ q_out, unsigned short* __restrict__ k_out,
    unsigned short* __restrict__ v_out, int M, int N, int K) {
  const int t = threadIdx.x;
  const int wave = t >> 6, lane = t & 63;
  const int m16 = lane & 15, quad = lane >> 4;
  const int wr = wave >> 1, wc = wave & 1;
  const int bm = blockIdx.y * 128, bn = blockIdx.x * 128;

  __shared__ unsigned short As[128 * 64];   // 16 KB
  __shared__ unsigned short Bs[128 * 64];   // 16 KB

  v4f acc[4][4];
#pragma unroll
  for (int mi = 0; mi < 4; mi++)
#pragma unroll
    for (int ni = 0; ni < 4; ni++) acc[mi][ni] = (v4f){0.f, 0.f, 0.f, 0.f};

  // staging addresses (see header comment)
  const int rS = t >> 3;
  const int jS = (t & 7) ^ (((rS & 3) << 1) | ((rS >> 3) & 1));
  const unsigned short* gA = A + (size_t)(bm + rS) * K + jS * 8;
  const unsigned short* gB = Bt + (size_t)(bn + rS) * K + jS * 8;

  // fragment-read bases
  const int sA = ((m16 & 3) << 1) | ((m16 >> 3) & 1);
  const int c0 = quad ^ sA;                       // chunk slot for kk=0
  const unsigned short* aBase = &As[(wr * 64 + m16) * 64];
  const unsigned short* bBase = &Bs[(wc * 64 + m16) * 64];

  const int nkt = K >> 6;
  for (int kt = 0; kt < nkt; ++kt) {
#pragma unroll
    for (int i = 0; i < 4; ++i) {
      gld16(gA + (size_t)(i * 32) * K, &As[(i * 256 + t) * 8]);
      gld16(gB + (size_t)(i * 32) * K, &Bs[(i * 256 + t) * 8]);
    }
    gA += 64; gB += 64;
    __syncthreads();

#pragma unroll
    for (int kk = 0; kk < 2; ++kk) {
      const int co = (c0 ^ (kk * 4)) * 8;
      v8s a[4], b[4];
#pragma unroll
      for (int mi = 0; mi < 4; mi++)
        a[mi] = *(const v8s*)(aBase + mi * 16 * 64 + co);
#pragma unroll
      for (int ni = 0; ni < 4; ni++)
        b[ni] = *(const v8s*)(bBase + ni * 16 * 64 + co);
#pragma unroll
      for (int mi = 0; mi < 4; mi++)
#pragma unroll
        for (int ni = 0; ni < 4; ni++)
          acc[mi][ni] = __builtin_amdgcn_mfma_f32_16x16x32_bf16(a[mi], b[ni], acc[mi][ni], 0, 0, 0);
    }
    __syncthreads();
  }

  if (MODE == 0) {
#pragma unroll
    for (int mi = 0; mi < 4; mi++) {
#pragma unroll
      for (int ni = 0; ni < 4; ni++) {
        int col = bn + wc * 64 + ni * 16 + m16;
        int which = col >> 10;
        int h = (col >> 6) & 15, d = col & 63;
        float bv = bias[col];
        float sc = (which == 0) ? CL2E : 1.f;
        int row0 = bm + wr * 64 + mi * 16 + quad * 4;
        int bb = row0 >> 11, tt0 = row0 & 2047;
        float v0 = (acc[mi][ni][0] + bv) * sc, v1 = (acc[mi][ni][1] + bv) * sc;
        float v2 = (acc[mi][ni][2] + bv) * sc, v3 = (acc[mi][ni][3] + bv) * sc;
        if (which == 2) {
          ushort4 pk; pk.x = f2bf(v0); pk.y = f2bf(v1); pk.z = f2bf(v2); pk.w = f2bf(v3);
          *(ushort4*)&v_out[(((size_t)(bb * NH + h)) * DH + d) * NT + tt0] = pk;
        } else {
          unsigned short* dst = (which == 0) ? q_out : k_out;
          size_t idx = (((size_t)(bb * NH + h)) * NT + tt0) * DH + d;
          dst[idx] = f2bf(v0); dst[idx + DH] = f2bf(v1);
          dst[idx + 2 * DH] = f2bf(v2); dst[idx + 3 * DH] = f2bf(v3);
        }
      }
    }
  } else {
#pragma unroll
    for (int mi = 0; mi < 4; mi++) {
#pragma unroll
      for (int ni = 0; ni < 4; ni++) {
        int col = bn + wc * 64 + ni * 16 + m16;
        float bv = bias[col];
#pragma unroll
        for (int r = 0; r < 4; r++) {
          int row = bm + wr * 64 + mi * 16 + quad * 4 + r;
          Co[(size_t)row * N + col] = acc[mi][ni][r] + bv;
        }
      }
    }
  }
}

// ---------------------------------------------------------------- flash attention
// (unchanged from R7 — verified: QBLK=128, KVBLK=64, 16KB LDS, 4 blocks/CU.
//  Flash config FROZEN: R2/R3 dbuf, R4 grid-remap, R10 QBLK=64 all failed
//  refcheck; R8 QBLK=256 neutral; R9 setprio slightly negative.)
// Q (pre-scaled by CL2E),K: (B*H, T, Dh) bf16. Vt: (B*H, Dh, T) bf16.
// Out: (B*T, EMB) bf16.  Block = 4 waves, 128 Q rows (32/wave).
__global__ __launch_bounds__(256, 4) void flash_attn(
    const unsigned short* __restrict__ Qg, const unsigned short* __restrict__ Kg,
    const unsigned short* __restrict__ Vtg, unsigned short* __restrict__ Og) {
  const int t = threadIdx.x;
  const int w = t >> 6, lane = t & 63;
  const int m16 = lane & 15, quad = lane >> 4;
  const int qt = blockIdx.x, bh = blockIdx.y;
  const int b = bh >> 4, h = bh & 15;

  __shared__ unsigned short Ks[64 * 64];      // swizzled [key][d]   (8 KB)
  __shared__ unsigned short Vt[64 * 64];      // swizzled [d][key]   (8 KB)

  const size_t baseq = (size_t)bh * NT * DH;  // Q,K: (t,d)
  const size_t basev = (size_t)bh * DH * NT;  // Vt:  (d,t)

  // Q fragments: two 16-row tiles (B-operand layout == A layout for this shape)
  v8s qf[2][2];
#pragma unroll
  for (int tq = 0; tq < 2; tq++) {
    int qrow = qt * 128 + w * 32 + tq * 16 + m16;
#pragma unroll
    for (int kk = 0; kk < 2; kk++)
      qf[tq][kk] = *(const v8s*)&Qg[baseq + (size_t)qrow * DH + kk * 32 + quad * 8];
  }

  v4f accO[2][4], accL[2];
#pragma unroll
  for (int tq = 0; tq < 2; tq++) {
#pragma unroll
    for (int i = 0; i < 4; i++) accO[tq][i] = (v4f){0.f, 0.f, 0.f, 0.f};
    accL[tq] = (v4f){0.f, 0.f, 0.f, 0.f};
  }
  const v4f zero4 = (v4f){0.f, 0.f, 0.f, 0.f};
  const v8s ones8 = (v8s){(short)0x3F80, (short)0x3F80, (short)0x3F80, (short)0x3F80,
                          (short)0x3F80, (short)0x3F80, (short)0x3F80, (short)0x3F80};

  // ---- loop-invariant addresses
  const int rK = t >> 3, jK = (t & 7) ^ (((rK & 3) << 1) | ((rK >> 3) & 1));
  const int dV = t >> 3, jV = (t & 7) ^ (dV & 7);
  const unsigned short* gK = &Kg[baseq + (size_t)rK * DH + jK * 8];
  const unsigned short* gV = &Vtg[basev + (size_t)dV * NT + jV * 8];
  // K-frag bases (A-operand of St): permuted rows, chunks kk*4+quad, swizzle sP.
  const int keyA = ((m16 >> 2) << 3) | (m16 & 3);                 // tile a row->key
  const int sP = ((m16 & 3) << 1) | ((m16 >> 2) & 1);             // == s(keyA) == s(keyA+4)
  const unsigned short* ka0 = &Ks[ keyA      * 64 + ((0 + quad) ^ sP) * 8];  // kk=0
  const unsigned short* ka1 = &Ks[ keyA      * 64 + ((4 + quad) ^ sP) * 8];  // kk=1
  const unsigned short* kb0 = &Ks[(keyA + 4) * 64 + ((0 + quad) ^ sP) * 8];
  const unsigned short* kb1 = &Ks[(keyA + 4) * 64 + ((4 + quad) ^ sP) * 8];
  // V-frag base (A-operand of PV, 16x16x32): row d = ni2*16+m16,
  // keys nj*32 + quad*8..+7 = chunk c = nj*4+quad at slot c ^ (m16&7).
  const unsigned short* vBase = &Vt[m16 * 64];

  for (int kt = 0; kt < NT / 64; ++kt) {
    __syncthreads();  // all waves done reading previous Ks/Vt
#pragma unroll
    for (int i = 0; i < 2; ++i)
      gld16(gK + (size_t)(i * 32) * DH, &Ks[(i * 256 + t) * 8]);
#pragma unroll
    for (int i = 0; i < 2; ++i)
      gld16(gV + (size_t)(i * 32) * NT, &Vt[(i * 256 + t) * 8]);
    gK += 64 * DH;
    gV += 64;
    __syncthreads();

    // St tile-pairs -> exp2 -> packed v8s P fragments (in-register, no LDS)
    v8s pp[2][2];
#pragma unroll
    for (int nj = 0; nj < 2; nj++) {
      const int o = nj * 2048;                 // 32 keys * 64 shorts
      v8s kA0 = *(const v8s*)(ka0 + o);
      v8s kA1 = *(const v8s*)(ka1 + o);
      v8s kB0 = *(const v8s*)(kb0 + o);
      v8s kB1 = *(const v8s*)(kb1 + o);
      v4f s0a = __builtin_amdgcn_mfma_f32_16x16x32_bf16(kA0, qf[0][0], zero4, 0, 0, 0);
      s0a = __builtin_amdgcn_mfma_f32_16x16x32_bf16(kA1, qf[0][1], s0a, 0, 0, 0);
      v4f s1a = __builtin_amdgcn_mfma_f32_16x16x32_bf16(kA0, qf[1][0], zero4, 0, 0, 0);
      s1a = __builtin_amdgcn_mfma_f32_16x16x32_bf16(kA1, qf[1][1], s1a, 0, 0, 0);
      v4f s0b = __builtin_amdgcn_mfma_f32_16x16x32_bf16(kB0, qf[0][0], zero4, 0, 0, 0);
      s0b = __builtin_amdgcn_mfma_f32_16x16x32_bf16(kB1, qf[0][1], s0b, 0, 0, 0);
      v4f s1b = __builtin_amdgcn_mfma_f32_16x16x32_bf16(kB0, qf[1][0], zero4, 0, 0, 0);
      s1b = __builtin_amdgcn_mfma_f32_16x16x32_bf16(kB1, qf[1][1], s1b, 0, 0, 0);
      pp[0][nj] = exppack8(s0a, s0b);
      pp[1][nj] = exppack8(s1a, s1b);
    }

    // O^T += V^T * P  (16x16x32, P straight from registers); L += 1 * P
#pragma unroll
    for (int nj = 0; nj < 2; nj++) {
      accL[0] = __builtin_amdgcn_mfma_f32_16x16x32_bf16(ones8, pp[0][nj], accL[0], 0, 0, 0);
      accL[1] = __builtin_amdgcn_mfma_f32_16x16x32_bf16(ones8, pp[1][nj], accL[1], 0, 0, 0);
      const int slot = ((nj * 4 + quad) ^ (m16 & 7)) * 8;
#pragma unroll
      for (int ni2 = 0; ni2 < 4; ni2++) {
        v8s vf = *(const v8s*)(vBase + ni2 * 16 * 64 + slot);
        accO[0][ni2] = __builtin_amdgcn_mfma_f32_16x16x32_bf16(vf, pp[0][nj], accO[0][ni2], 0, 0, 0);
        accO[1][ni2] = __builtin_amdgcn_mfma_f32_16x16x32_bf16(vf, pp[1][nj], accO[1][ni2], 0, 0, 0);
      }
    }
  }

  // epilogue: O^T tiles: lane (col=qrow=m16, quad) holds d = ni2*16+quad*4+r.
  // accL: all r-copies equal L[qrow=m16]. 4 consecutive d -> one 8B store.
#pragma unroll
  for (int tq = 0; tq < 2; tq++) {
    float inv = 1.f / accL[tq][0];
    int trow = qt * 128 + w * 32 + tq * 16 + m16;
    size_t ob = ((size_t)b * NT + trow) * EMB + h * DH;
#pragma unroll
    for (int ni2 = 0; ni2 < 4; ni2++) {
      float v0 = accO[tq][ni2][0] * inv, v1 = accO[tq][ni2][1] * inv;
      float v2 = accO[tq][ni2][2] * inv, v3 = accO[tq][ni2][3] * inv;
      uint2 d;
      d.x = (unsigned int)f2bf(v0) | ((unsigned int)f2bf(v1) << 16);
      d.y = (unsigned int)f2bf(v2) | ((unsigned int)f2bf(v3) << 16);
      *(uint2*)&Og[ob + ni2 * 16 + quad * 4] = d;
    }
  }
}

// ---------------------------------------------------------------- launch
extern "C" void kernel_launch(void* const* d_in, const int* in_sizes, int n_in,
                              void* d_out, int out_size, void* d_ws, size_t ws_size,
                              hipStream_t stream) {
  const float* x     = (const float*)d_in[0];
  const float* w_qkv = (const float*)d_in[1];
  const float* b_qkv = (const float*)d_in[2];
  const float* w_out = (const float*)d_in[3];
  const float* b_out = (const float*)d_in[4];
  float* out = (float*)d_out;

  unsigned short* xb    = (unsigned short*)d_ws;            // 8192*1024
  unsigned short* wqkvT = xb    + (size_t)BT * EMB;         // 3072*1024
  unsigned short* woutT = wqkvT + (size_t)NQKV * EMB;       // 1024*1024
  unsigned short* qb    = woutT + (size_t)EMB * EMB;        // (b,h,t,d), pre-scaled
  unsigned short* kb    = qb    + (size_t)NB * NH * NT * DH; // (b,h,t,d)
  unsigned short* vb    = kb    + (size_t)NB * NH * NT * DH; // (b,h,d,t) transposed!
  unsigned short* ao    = vb    + (size_t)NB * NH * NT * DH; // 8192*1024

  prep_k<<<8192, 256, 0, stream>>>(x, xb, w_qkv, wqkvT, w_out, woutT);

  gemm_bt<0><<<dim3(NQKV / 128, BT / 128), 256, 0, stream>>>(
      xb, wqkvT, b_qkv, nullptr, qb, kb, vb, BT, NQKV, EMB);

  flash_attn<<<dim3(NT / 128, NB * NH), 256, 0, stream>>>(qb, kb, vb, ao);

  gemm_bt<1><<<dim3(EMB / 128, BT / 128), 256, 0, stream>>>(
      ao, woutT, b_out, out, nullptr, nullptr, nullptr, BT, EMB, EMB);
}